// Round 1
// baseline (7828.535 us; speedup 1.0000x reference)
//
#include <hip/hip_runtime.h>
#include <math.h>

#define U_ 256
#define NN 128
#define MM 64
#define SS 3
#define OUT_ 8
#define CLIPV 20.0f
#define IN_DIM_ 9
#define HH 2
#define PER_ 70
#define PP 268   // H*PER + WH*2*M = 140+128
#define B_ 128
#define T_ 130
#define TSTART 65  // max_seq_len+1
#define CTRL_ 73   // IN_DIM + R*M

__device__ __forceinline__ float sigf(float x){ return 1.0f/(1.0f+expf(-x)); }
__device__ __forceinline__ float splus(float x){ return log1pf(expf(x)); }
__device__ __forceinline__ float clipf(float x){ return fminf(fmaxf(x,-CLIPV),CLIPV); }

__global__ __launch_bounds__(512,1) void ntm_kernel(
    const float* __restrict__ inputs, const float* __restrict__ W_x,
    const float* __restrict__ W_h, const float* __restrict__ b_lstm,
    const float* __restrict__ W_p, const float* __restrict__ b_p,
    const float* __restrict__ W_o, const float* __restrict__ b_o,
    const float* __restrict__ r0, const float* __restrict__ w0,
    float* __restrict__ out)
{
    const int b = blockIdx.x;
    const int t = threadIdx.x;

    __shared__ float Mem[NN][MM+1];       // padded rows: bank = (n+m)%32
    __shared__ float hbuf[U_], cbuf[U_];
    __shared__ float gates[4*U_];
    __shared__ float ctrl[CTRL_];
    __shared__ float prm[PP];
    __shared__ float kv[HH][MM];
    __shared__ float ebuf[MM], abuf[MM];
    __shared__ float scal[16];            // 0,1 beta; 2,3 g; 4,5 gamma; 6..11 s; 12,13 kn
    __shared__ float innr[HH][NN];
    __shared__ float Mn[NN];
    __shared__ float wgs[HH][NN];
    __shared__ float wcur[HH][NN];
    __shared__ float wprev[HH][NN];
    __shared__ float rpart[4][MM];
    __shared__ float rbuf[MM];

    // ---- init state ----
    for (int idx=t; idx<NN*MM; idx+=512){ Mem[idx>>6][idx&63] = 1e-6f; }
    if (t < U_){ hbuf[t]=0.f; cbuf[t]=0.f; }
    if (t < MM) rbuf[t] = tanhf(r0[t]);
    if (t < 2*64){  // wprev = softmax(w0) per head; wave h handles head h
        int h = t>>6, l = t&63;
        float v0 = w0[h*NN + l], v1 = w0[h*NN + l + 64];
        float mx = fmaxf(v0,v1);
        for (int off=32; off>=1; off>>=1) mx = fmaxf(mx, __shfl_xor(mx, off));
        float e0 = expf(v0-mx), e1 = expf(v1-mx);
        float s = e0+e1;
        for (int off=32; off>=1; off>>=1) s += __shfl_xor(s, off);
        wprev[h][l] = e0/s; wprev[h][l+64] = e1/s;
    }
    __syncthreads();

    for (int step=0; step<T_; ++step){
        // A: controller input = [x_t, r_prev]
        if (t < IN_DIM_) ctrl[t] = inputs[(b*T_ + step)*IN_DIM_ + t];
        else if (t < CTRL_) ctrl[t] = rbuf[t-IN_DIM_];
        __syncthreads();

        // B: gates = ctrl@W_x + h@W_h + b  (each thread: 2 outputs, float2 loads)
        {
            int j0 = t*2;
            float acc0 = b_lstm[j0], acc1 = b_lstm[j0+1];
            for (int i=0;i<CTRL_;++i){
                float v = ctrl[i];
                float2 w = *(const float2*)(W_x + i*1024 + j0);
                acc0 = fmaf(v, w.x, acc0); acc1 = fmaf(v, w.y, acc1);
            }
            for (int i=0;i<U_;++i){
                float v = hbuf[i];
                float2 w = *(const float2*)(W_h + i*1024 + j0);
                acc0 = fmaf(v, w.x, acc0); acc1 = fmaf(v, w.y, acc1);
            }
            gates[j0]=acc0; gates[j0+1]=acc1;
        }
        __syncthreads();

        // C: LSTM cell update
        if (t < U_){
            float gi = gates[t], gf = gates[t+U_], gg_ = gates[t+2*U_], go = gates[t+3*U_];
            float c = sigf(gf)*cbuf[t] + sigf(gi)*tanhf(gg_);
            cbuf[t] = c;
            hbuf[t] = sigf(go)*tanhf(c);
        }
        __syncthreads();

        // D: params = clip(h@W_p + b_p)
        if (t < PP){
            float acc = b_p[t];
            for (int i=0;i<U_;++i) acc = fmaf(hbuf[i], W_p[i*PP + t], acc);
            prm[t] = clipf(acc);
        }
        __syncthreads();

        // E: head params
        if (t < 2*MM){ int h=t>>6, m=t&63; kv[h][m] = tanhf(prm[h*PER_+m]); }
        else if (t < 3*MM){ int m=t-2*MM; ebuf[m] = sigf(prm[HH*PER_ + m]); }
        else if (t < 4*MM){ int m=t-3*MM; abuf[m] = tanhf(prm[HH*PER_ + MM + m]); }
        else if (t < 4*MM+2){
            int h = t-4*MM;
            const float* hp = prm + h*PER_;
            scal[h]   = splus(hp[MM]);               // beta
            scal[2+h] = sigf(hp[MM+1]);              // g
            scal[4+h] = 1.0f + splus(hp[MM+2+SS]);   // gamma
            float a0=hp[MM+2], a1=hp[MM+3], a2=hp[MM+4];
            float mx = fmaxf(a0,fmaxf(a1,a2));
            float e0=expf(a0-mx), e1=expf(a1-mx), e2=expf(a2-mx);
            float s = e0+e1+e2;
            scal[6+3*h]=e0/s; scal[7+3*h]=e1/s; scal[8+3*h]=e2/s;
        }
        __syncthreads();

        // F: inner products, memory norms, key norms
        if (t < 2*NN){
            int h=t>>7, n=t&127;
            float s=0.f;
            for (int m=0;m<MM;++m) s = fmaf(kv[h][m], Mem[n][m], s);
            innr[h][n]=s;
        } else if (t < 3*NN){
            int n=t-2*NN;
            float s=0.f;
            for (int m=0;m<MM;++m){ float v=Mem[n][m]; s=fmaf(v,v,s); }
            Mn[n]=sqrtf(s);
        } else if (t < 3*NN+2){
            int h=t-3*NN;
            float s=0.f;
            for (int m=0;m<MM;++m){ float v=kv[h][m]; s=fmaf(v,v,s); }
            scal[12+h]=sqrtf(s);
        }
        __syncthreads();

        // G1: content softmax + interpolation gate -> wg  (wave h per head)
        if (t < 2*64){
            int h=t>>6, l=t&63;
            float kn = scal[12+h], beta = scal[h], g = scal[2+h];
            float bk0 = beta * innr[h][l]   /(kn*Mn[l]   +1e-8f);
            float bk1 = beta * innr[h][l+64]/(kn*Mn[l+64]+1e-8f);
            float mx = fmaxf(bk0,bk1);
            for (int off=32; off>=1; off>>=1) mx = fmaxf(mx, __shfl_xor(mx, off));
            float e0=expf(bk0-mx), e1=expf(bk1-mx);
            float s=e0+e1;
            for (int off=32; off>=1; off>>=1) s += __shfl_xor(s, off);
            float wc0=e0/s, wc1=e1/s;
            wgs[h][l]    = g*wc0 + (1.f-g)*wprev[h][l];
            wgs[h][l+64] = g*wc1 + (1.f-g)*wprev[h][l+64];
        }
        __syncthreads();

        // G2: shift conv, sharpen, normalize
        if (t < 2*64){
            int h=t>>6, l=t&63;
            float gamma = scal[4+h];
            float s0=scal[6+3*h], s1=scal[7+3*h], s2=scal[8+3*h];
            int n0=l, n1=l+64;
            float wt0 = s0*wgs[h][(n0+1)&127] + s1*wgs[h][n0] + s2*wgs[h][(n0+127)&127];
            float wt1 = s0*wgs[h][(n1+1)&127] + s1*wgs[h][n1] + s2*wgs[h][(n1+127)&127];
            float wp0 = powf(wt0, gamma), wp1 = powf(wt1, gamma);
            float s = wp0+wp1;
            for (int off=32; off>=1; off>>=1) s += __shfl_xor(s, off);
            float inv = 1.0f/(s+1e-8f);
            float v0 = wp0*inv, v1 = wp1*inv;
            wcur[h][n0]=v0; wcur[h][n1]=v1;
            wprev[h][n0]=v0; wprev[h][n1]=v1;
        }
        __syncthreads();

        // H: memory write (head 1 is the write head)
        for (int idx=t; idx<NN*MM; idx+=512){
            int n=idx>>6, m=idx&63;
            float ww = wcur[1][n];
            Mem[n][m] = Mem[n][m]*(1.0f - ww*ebuf[m]) + ww*abuf[m];
        }
        __syncthreads();

        // I: read head: r = w_r @ Mem  (4 partials per m)
        if (t < 256){
            int m=t&63, q=t>>6;
            float s=0.f;
            for (int n=q*32;n<q*32+32;++n) s = fmaf(wcur[0][n], Mem[n][m], s);
            rpart[q][m]=s;
        }
        __syncthreads();
        if (t < MM) rbuf[t] = rpart[0][t]+rpart[1][t]+rpart[2][t]+rpart[3][t];
        __syncthreads();

        // J: out = sigmoid(clip([h,r]@W_o + b_o))
        if (t < 256){
            int o=t>>5, i0=t&31;
            float s=0.f;
            for (int j=0;j<10;++j){
                int i=i0+32*j;
                float v = (i<U_)? hbuf[i] : rbuf[i-U_];
                s = fmaf(v, W_o[i*OUT_ + o], s);
            }
            for (int off=16; off>=1; off>>=1) s += __shfl_xor(s, off, 32);
            if (i0==0 && step>=TSTART){
                float logit = clipf(s + b_o[o]);
                out[((b*(T_-TSTART)) + (step-TSTART))*OUT_ + o] = sigf(logit);
            }
        }
        __syncthreads();
    }
}

extern "C" void kernel_launch(void* const* d_in, const int* in_sizes, int n_in,
                              void* d_out, int out_size, void* d_ws, size_t ws_size,
                              hipStream_t stream) {
    const float* inputs = (const float*)d_in[0];
    const float* W_x    = (const float*)d_in[1];
    const float* W_h    = (const float*)d_in[2];
    const float* b_lstm = (const float*)d_in[3];
    const float* W_p    = (const float*)d_in[4];
    const float* b_p    = (const float*)d_in[5];
    const float* W_o    = (const float*)d_in[6];
    const float* b_o    = (const float*)d_in[7];
    const float* r0     = (const float*)d_in[8];
    const float* w0     = (const float*)d_in[9];
    float* out = (float*)d_out;

    ntm_kernel<<<B_, 512, 0, stream>>>(inputs, W_x, W_h, b_lstm, W_p, b_p,
                                       W_o, b_o, r0, w0, out);
}

// Round 2
// 6862.001 us; speedup vs baseline: 1.1409x; 1.1409x over previous
//
#include <hip/hip_runtime.h>
#include <math.h>

#define U_ 256
#define NN 128
#define MM 64
#define SS 3
#define OUT_ 8
#define CLIPV 20.0f
#define IN_DIM_ 9
#define HH 2
#define PER_ 70
#define PP 268   // H*PER + WH*2*M = 140+128
#define B_ 128
#define T_ 130
#define TSTART 65  // max_seq_len+1
#define CTRL_ 73   // IN_DIM + R*M

__device__ __forceinline__ float sigf(float x){ return 1.0f/(1.0f+expf(-x)); }
__device__ __forceinline__ float splus(float x){ return log1pf(expf(x)); }
__device__ __forceinline__ float clipf(float x){ return fminf(fmaxf(x,-CLIPV),CLIPV); }

__global__ __launch_bounds__(1024,1) void ntm_kernel(
    const float* __restrict__ inputs, const float* __restrict__ W_x,
    const float* __restrict__ W_h, const float* __restrict__ b_lstm,
    const float* __restrict__ W_p, const float* __restrict__ b_p,
    const float* __restrict__ W_o, const float* __restrict__ b_o,
    const float* __restrict__ r0, const float* __restrict__ w0,
    float* __restrict__ out)
{
    const int b = blockIdx.x;
    const int t = threadIdx.x;

    __shared__ float Mem[NN][MM+1];       // padded rows
    __shared__ float hbuf[U_], cbuf[U_];
    __shared__ float gates[4*U_];
    __shared__ float ctrl[CTRL_];
    __shared__ float prm[PP];
    __shared__ float kv[HH][MM];
    __shared__ float ebuf[MM], abuf[MM];
    __shared__ float scal[16];            // 0,1 beta; 2,3 g; 4,5 gamma; 6..11 s; 12,13 kn
    __shared__ float innr[HH][NN];
    __shared__ float Mn[NN];
    __shared__ float wgs[HH][NN];
    __shared__ float wcur[HH][NN];
    __shared__ float wprev[HH][NN];
    __shared__ float rpart[16][MM];
    __shared__ float rbuf[MM];

    // ---- init state ----
    for (int idx=t; idx<NN*MM; idx+=1024){ Mem[idx>>6][idx&63] = 1e-6f; }
    if (t < U_){ hbuf[t]=0.f; cbuf[t]=0.f; }
    if (t < MM) rbuf[t] = tanhf(r0[t]);
    if (t < 2*64){  // wprev = softmax(w0) per head; wave h handles head h
        int h = t>>6, l = t&63;
        float v0 = w0[h*NN + l], v1 = w0[h*NN + l + 64];
        float mx = fmaxf(v0,v1);
        for (int off=32; off>=1; off>>=1) mx = fmaxf(mx, __shfl_xor(mx, off));
        float e0 = expf(v0-mx), e1 = expf(v1-mx);
        float s = e0+e1;
        for (int off=32; off>=1; off>>=1) s += __shfl_xor(s, off);
        wprev[h][l] = e0/s; wprev[h][l+64] = e1/s;
    }
    __syncthreads();

    for (int step=0; step<T_; ++step){
        // A: controller input = [x_t, r_prev]
        if (t < IN_DIM_) ctrl[t] = inputs[(b*T_ + step)*IN_DIM_ + t];
        else if (t < CTRL_) ctrl[t] = rbuf[t-IN_DIM_];
        __syncthreads();

        // B: gates = ctrl@W_x + h@W_h + b
        // 256 output-groups of 4 (float4), 4-way K split across lanes, shfl reduce
        {
            const int g = t>>2, q = t&3, j0 = g*4;
            const int k0 = (q*329)>>2, k1 = ((q+1)*329)>>2;
            float ax=0.f, ay=0.f, az=0.f, aw=0.f;
            const int kx1 = (k1 < CTRL_) ? k1 : CTRL_;
            #pragma unroll 4
            for (int i=k0; i<kx1; ++i){
                float v = ctrl[i];
                float4 w = *(const float4*)(W_x + i*1024 + j0);
                ax = fmaf(v,w.x,ax); ay = fmaf(v,w.y,ay);
                az = fmaf(v,w.z,az); aw = fmaf(v,w.w,aw);
            }
            const int kh0 = (k0 > CTRL_) ? k0 : CTRL_;
            #pragma unroll 4
            for (int i=kh0; i<k1; ++i){
                float v = hbuf[i-CTRL_];
                float4 w = *(const float4*)(W_h + (i-CTRL_)*1024 + j0);
                ax = fmaf(v,w.x,ax); ay = fmaf(v,w.y,ay);
                az = fmaf(v,w.z,az); aw = fmaf(v,w.w,aw);
            }
            ax += __shfl_xor(ax,1); ay += __shfl_xor(ay,1);
            az += __shfl_xor(az,1); aw += __shfl_xor(aw,1);
            ax += __shfl_xor(ax,2); ay += __shfl_xor(ay,2);
            az += __shfl_xor(az,2); aw += __shfl_xor(aw,2);
            if (q==0){
                float4 bb = *(const float4*)(b_lstm + j0);
                gates[j0  ] = ax + bb.x;
                gates[j0+1] = ay + bb.y;
                gates[j0+2] = az + bb.z;
                gates[j0+3] = aw + bb.w;
            }
        }
        __syncthreads();

        // C: LSTM cell update
        if (t < U_){
            float gi = gates[t], gf = gates[t+U_], gg_ = gates[t+2*U_], go = gates[t+3*U_];
            float c = sigf(gf)*cbuf[t] + sigf(gi)*tanhf(gg_);
            cbuf[t] = c;
            hbuf[t] = sigf(go)*tanhf(c);
        }
        __syncthreads();

        // D: params = clip(h@W_p + b_p)
        // 67 output-groups of 4 (float4), 8-way K split, shfl reduce
        if (t < 536){
            const int g = t>>3, q = t&7, j0 = g*4;
            const int k0 = q*32, k1 = k0+32;
            float ax=0.f, ay=0.f, az=0.f, aw=0.f;
            #pragma unroll 4
            for (int i=k0; i<k1; ++i){
                float v = hbuf[i];
                float4 w = *(const float4*)(W_p + i*PP + j0);
                ax = fmaf(v,w.x,ax); ay = fmaf(v,w.y,ay);
                az = fmaf(v,w.z,az); aw = fmaf(v,w.w,aw);
            }
            ax += __shfl_xor(ax,1); ay += __shfl_xor(ay,1);
            az += __shfl_xor(az,1); aw += __shfl_xor(aw,1);
            ax += __shfl_xor(ax,2); ay += __shfl_xor(ay,2);
            az += __shfl_xor(az,2); aw += __shfl_xor(aw,2);
            ax += __shfl_xor(ax,4); ay += __shfl_xor(ay,4);
            az += __shfl_xor(az,4); aw += __shfl_xor(aw,4);
            if (q==0){
                prm[j0  ] = clipf(ax + b_p[j0  ]);
                prm[j0+1] = clipf(ay + b_p[j0+1]);
                prm[j0+2] = clipf(az + b_p[j0+2]);
                prm[j0+3] = clipf(aw + b_p[j0+3]);
            }
        }
        __syncthreads();

        // E: head params
        if (t < 2*MM){ int h=t>>6, m=t&63; kv[h][m] = tanhf(prm[h*PER_+m]); }
        else if (t < 3*MM){ int m=t-2*MM; ebuf[m] = sigf(prm[HH*PER_ + m]); }
        else if (t < 4*MM){ int m=t-3*MM; abuf[m] = tanhf(prm[HH*PER_ + MM + m]); }
        else if (t < 4*MM+2){
            int h = t-4*MM;
            const float* hp = prm + h*PER_;
            scal[h]   = splus(hp[MM]);               // beta
            scal[2+h] = sigf(hp[MM+1]);              // g
            scal[4+h] = 1.0f + splus(hp[MM+2+SS]);   // gamma
            float a0=hp[MM+2], a1=hp[MM+3], a2=hp[MM+4];
            float mx = fmaxf(a0,fmaxf(a1,a2));
            float e0=expf(a0-mx), e1=expf(a1-mx), e2=expf(a2-mx);
            float s = e0+e1+e2;
            scal[6+3*h]=e0/s; scal[7+3*h]=e1/s; scal[8+3*h]=e2/s;
        }
        __syncthreads();

        // F: inner products, memory norms, key norms
        if (t < 2*NN){
            int h=t>>7, n=t&127;
            float s=0.f;
            #pragma unroll 8
            for (int m=0;m<MM;++m) s = fmaf(kv[h][m], Mem[n][m], s);
            innr[h][n]=s;
        } else if (t < 3*NN){
            int n=t-2*NN;
            float s=0.f;
            #pragma unroll 8
            for (int m=0;m<MM;++m){ float v=Mem[n][m]; s=fmaf(v,v,s); }
            Mn[n]=sqrtf(s);
        } else if (t < 3*NN+2){
            int h=t-3*NN;
            float s=0.f;
            for (int m=0;m<MM;++m){ float v=kv[h][m]; s=fmaf(v,v,s); }
            scal[12+h]=sqrtf(s);
        }
        __syncthreads();

        // G1: content softmax + interpolation gate -> wg  (wave h per head)
        if (t < 2*64){
            int h=t>>6, l=t&63;
            float kn = scal[12+h], beta = scal[h], g = scal[2+h];
            float bk0 = beta * innr[h][l]   /(kn*Mn[l]   +1e-8f);
            float bk1 = beta * innr[h][l+64]/(kn*Mn[l+64]+1e-8f);
            float mx = fmaxf(bk0,bk1);
            for (int off=32; off>=1; off>>=1) mx = fmaxf(mx, __shfl_xor(mx, off));
            float e0=expf(bk0-mx), e1=expf(bk1-mx);
            float s=e0+e1;
            for (int off=32; off>=1; off>>=1) s += __shfl_xor(s, off);
            float wc0=e0/s, wc1=e1/s;
            wgs[h][l]    = g*wc0 + (1.f-g)*wprev[h][l];
            wgs[h][l+64] = g*wc1 + (1.f-g)*wprev[h][l+64];
        }
        __syncthreads();

        // G2: shift conv, sharpen, normalize
        if (t < 2*64){
            int h=t>>6, l=t&63;
            float gamma = scal[4+h];
            float s0=scal[6+3*h], s1=scal[7+3*h], s2=scal[8+3*h];
            int n0=l, n1=l+64;
            float wt0 = s0*wgs[h][(n0+1)&127] + s1*wgs[h][n0] + s2*wgs[h][(n0+127)&127];
            float wt1 = s0*wgs[h][(n1+1)&127] + s1*wgs[h][n1] + s2*wgs[h][(n1+127)&127];
            float wp0 = powf(wt0, gamma), wp1 = powf(wt1, gamma);
            float s = wp0+wp1;
            for (int off=32; off>=1; off>>=1) s += __shfl_xor(s, off);
            float inv = 1.0f/(s+1e-8f);
            float v0 = wp0*inv, v1 = wp1*inv;
            wcur[h][n0]=v0; wcur[h][n1]=v1;
            wprev[h][n0]=v0; wprev[h][n1]=v1;
        }
        __syncthreads();

        // H: memory write (head 1 is the write head)
        for (int idx=t; idx<NN*MM; idx+=1024){
            int n=idx>>6, m=idx&63;
            float ww = wcur[1][n];
            Mem[n][m] = Mem[n][m]*(1.0f - ww*ebuf[m]) + ww*abuf[m];
        }
        __syncthreads();

        // I: read head: r = w_r @ Mem  (16 partials per m)
        {
            int m=t&63, q=t>>6;
            float s=0.f;
            #pragma unroll 8
            for (int n=q*8;n<q*8+8;++n) s = fmaf(wcur[0][n], Mem[n][m], s);
            rpart[q][m]=s;
        }
        __syncthreads();
        if (t < MM){
            float s=0.f;
            #pragma unroll
            for (int k=0;k<16;++k) s += rpart[k][t];
            rbuf[t] = s;
        }
        __syncthreads();

        // J: out = sigmoid(clip([h,r]@W_o + b_o))
        if (t < 256){
            int o=t>>5, i0=t&31;
            float s=0.f;
            for (int j=0;j<10;++j){
                int i=i0+32*j;
                float v = (i<U_)? hbuf[i] : rbuf[i-U_];
                s = fmaf(v, W_o[i*OUT_ + o], s);
            }
            for (int off=16; off>=1; off>>=1) s += __shfl_xor(s, off, 32);
            if (i0==0 && step>=TSTART){
                float logit = clipf(s + b_o[o]);
                out[((b*(T_-TSTART)) + (step-TSTART))*OUT_ + o] = sigf(logit);
            }
        }
        __syncthreads();
    }
}

extern "C" void kernel_launch(void* const* d_in, const int* in_sizes, int n_in,
                              void* d_out, int out_size, void* d_ws, size_t ws_size,
                              hipStream_t stream) {
    const float* inputs = (const float*)d_in[0];
    const float* W_x    = (const float*)d_in[1];
    const float* W_h    = (const float*)d_in[2];
    const float* b_lstm = (const float*)d_in[3];
    const float* W_p    = (const float*)d_in[4];
    const float* b_p    = (const float*)d_in[5];
    const float* W_o    = (const float*)d_in[6];
    const float* b_o    = (const float*)d_in[7];
    const float* r0     = (const float*)d_in[8];
    const float* w0     = (const float*)d_in[9];
    float* out = (float*)d_out;

    ntm_kernel<<<B_, 1024, 0, stream>>>(inputs, W_x, W_h, b_lstm, W_p, b_p,
                                        W_o, b_o, r0, w0, out);
}

// Round 3
// 4248.471 us; speedup vs baseline: 1.8427x; 1.6152x over previous
//
#include <hip/hip_runtime.h>
#include <hip/hip_bf16.h>
#include <math.h>

#define U_ 256
#define NN 128
#define MM 64
#define SS 3
#define OUT_ 8
#define CLIPV 20.0f
#define IN_DIM_ 9
#define HH 2
#define PER_ 70
#define PP 268       // H*PER + WH*2*M
#define PPAD 272     // padded params
#define B_ 128
#define T_ 130
#define TSTART 65
#define CTRL_ 73
#define KTOT 329     // CTRL_ + U_

// ws layout (bytes)
#define WXH_OFF 0
#define WXH_ELEMS (KTOT*1024)              // 336896 bf16
#define WP_OFF   (WXH_ELEMS*2)             // 673792
#define WP_ELEMS (U_*PPAD)                 // 69632 bf16
#define BPP_OFF  (WP_OFF + WP_ELEMS*2)     // 813056
#define PREP_TOT (WXH_ELEMS + WP_ELEMS + PPAD)

__device__ __forceinline__ float sigf(float x){ return 1.0f/(1.0f+expf(-x)); }
__device__ __forceinline__ float splus(float x){ return log1pf(expf(x)); }
__device__ __forceinline__ float clipf(float x){ return fminf(fmaxf(x,-CLIPV),CLIPV); }
__device__ __forceinline__ float blo(unsigned u){ return __uint_as_float(u<<16); }
__device__ __forceinline__ float bhi(unsigned u){ return __uint_as_float(u & 0xffff0000u); }

__global__ void prep_kernel(const float* __restrict__ W_x, const float* __restrict__ W_h,
                            const float* __restrict__ W_p, const float* __restrict__ b_p,
                            __hip_bfloat16* __restrict__ wxh, __hip_bfloat16* __restrict__ wp,
                            float* __restrict__ bpp)
{
    for (int idx = blockIdx.x*blockDim.x + threadIdx.x; idx < PREP_TOT; idx += gridDim.x*blockDim.x){
        if (idx < WXH_ELEMS){
            int i = idx >> 10;
            wxh[idx] = __float2bfloat16(i < CTRL_ ? W_x[idx] : W_h[idx - CTRL_*1024]);
        } else if (idx < WXH_ELEMS + WP_ELEMS){
            int k = idx - WXH_ELEMS;
            int i = k / PPAD, j = k - i*PPAD;
            wp[k] = (j < PP) ? __float2bfloat16(W_p[i*PP + j]) : __float2bfloat16(0.0f);
        } else {
            int j = idx - WXH_ELEMS - WP_ELEMS;
            bpp[j] = (j < PP) ? b_p[j] : 0.0f;
        }
    }
}

__global__ __launch_bounds__(1024,1) void ntm_kernel(
    const float* __restrict__ inputs,
    const float* __restrict__ b_lstm,
    const float* __restrict__ W_o, const float* __restrict__ b_o,
    const float* __restrict__ r0, const float* __restrict__ w0,
    const __hip_bfloat16* __restrict__ wxh, const __hip_bfloat16* __restrict__ wp,
    const float* __restrict__ bpp,
    float* __restrict__ out)
{
    const int b = blockIdx.x;
    const int t = threadIdx.x;
    const int wv = t >> 6, ln = t & 63;

    __shared__ float Mem[NN][MM+1];
    __shared__ float hbuf[U_], cbuf[U_];
    __shared__ float gates[4*U_];
    __shared__ float vec[KTOT];
    __shared__ float prm[PPAD];
    __shared__ float kv[HH][MM];
    __shared__ float ebuf[MM], abuf[MM];
    __shared__ float scal[12];            // 0,1 beta; 2,3 g; 4,5 gamma; 6..11 s
    __shared__ float innr[HH][NN];
    __shared__ float Mn[NN];
    __shared__ float wgs[HH][NN];
    __shared__ float wcur[HH][NN];
    __shared__ float wprev[HH][NN];
    __shared__ float rbuf[MM];

    // ---- init state ----
    for (int idx=t; idx<NN*MM; idx+=1024){ Mem[idx>>6][idx&63] = 1e-6f; }
    if (t < NN) Mn[t] = sqrtf((float)MM * 1e-6f * 1e-6f);
    if (t < U_){ hbuf[t]=0.f; cbuf[t]=0.f; }
    if (t < MM) rbuf[t] = tanhf(r0[t]);
    if (t >= 128 && t < 256){  // wprev = softmax(w0)
        int h = (t-128)>>6, l = t&63;
        float v0 = w0[h*NN + l], v1 = w0[h*NN + l + 64];
        float mx = fmaxf(v0,v1);
        for (int off=32; off>=1; off>>=1) mx = fmaxf(mx, __shfl_xor(mx, off));
        float e0 = expf(v0-mx), e1 = expf(v1-mx);
        float s = e0+e1;
        for (int off=32; off>=1; off>>=1) s += __shfl_xor(s, off);
        wprev[h][l] = e0/s; wprev[h][l+64] = e1/s;
    }
    // vec for step 0: [x_0, tanh(r0), h=0]
    if (t >= 512 && t < 512+KTOT){
        int tt = t - 512;
        float v;
        if (tt < IN_DIM_)      v = inputs[b*T_*IN_DIM_ + tt];
        else if (tt < CTRL_)   v = tanhf(r0[tt-IN_DIM_]);
        else                   v = 0.f;
        vec[tt] = v;
    }
    __syncthreads();

    for (int step=0; step<T_; ++step){
        // B: gates = vec @ Wxh + b ; 128 col-groups of 8, 8-way K split
        {
            const int g = t>>3, q = t&7, j0 = g*8;
            const int k0 = (q*KTOT)>>3, k1 = ((q+1)*KTOT)>>3;
            float a0=0.f,a1=0.f,a2=0.f,a3=0.f,a4=0.f,a5=0.f,a6=0.f,a7=0.f;
            #pragma unroll 4
            for (int i=k0; i<k1; ++i){
                float v = vec[i];
                uint4 u = *(const uint4*)(wxh + (i<<10) + j0);
                a0 = fmaf(v, blo(u.x), a0); a1 = fmaf(v, bhi(u.x), a1);
                a2 = fmaf(v, blo(u.y), a2); a3 = fmaf(v, bhi(u.y), a3);
                a4 = fmaf(v, blo(u.z), a4); a5 = fmaf(v, bhi(u.z), a5);
                a6 = fmaf(v, blo(u.w), a6); a7 = fmaf(v, bhi(u.w), a7);
            }
            #pragma unroll
            for (int m=1; m<8; m<<=1){
                a0 += __shfl_xor(a0,m); a1 += __shfl_xor(a1,m);
                a2 += __shfl_xor(a2,m); a3 += __shfl_xor(a3,m);
                a4 += __shfl_xor(a4,m); a5 += __shfl_xor(a5,m);
                a6 += __shfl_xor(a6,m); a7 += __shfl_xor(a7,m);
            }
            if (q==0){
                float4 b0 = *(const float4*)(b_lstm + j0);
                float4 b1 = *(const float4*)(b_lstm + j0 + 4);
                *(float4*)&gates[j0]   = make_float4(a0+b0.x, a1+b0.y, a2+b0.z, a3+b0.w);
                *(float4*)&gates[j0+4] = make_float4(a4+b1.x, a5+b1.y, a6+b1.z, a7+b1.w);
            }
        }
        __syncthreads();

        // C: LSTM cell
        if (t < U_){
            float gi = gates[t], gf = gates[t+U_], gg_ = gates[t+2*U_], go = gates[t+3*U_];
            float c = sigf(gf)*cbuf[t] + sigf(gi)*tanhf(gg_);
            cbuf[t] = c;
            hbuf[t] = sigf(go)*tanhf(c);
        }
        __syncthreads();

        // D: params = clip(h@W_p + b_p); 34 col-groups of 8, 16-way K split
        if (t < 544){
            const int g = t>>4, q = t&15, j0 = g*8;
            const int k0 = q*16, k1 = k0+16;
            float a0=0.f,a1=0.f,a2=0.f,a3=0.f,a4=0.f,a5=0.f,a6=0.f,a7=0.f;
            #pragma unroll 4
            for (int i=k0; i<k1; ++i){
                float v = hbuf[i];
                uint4 u = *(const uint4*)(wp + i*PPAD + j0);
                a0 = fmaf(v, blo(u.x), a0); a1 = fmaf(v, bhi(u.x), a1);
                a2 = fmaf(v, blo(u.y), a2); a3 = fmaf(v, bhi(u.y), a3);
                a4 = fmaf(v, blo(u.z), a4); a5 = fmaf(v, bhi(u.z), a5);
                a6 = fmaf(v, blo(u.w), a6); a7 = fmaf(v, bhi(u.w), a7);
            }
            #pragma unroll
            for (int m=1; m<16; m<<=1){
                a0 += __shfl_xor(a0,m); a1 += __shfl_xor(a1,m);
                a2 += __shfl_xor(a2,m); a3 += __shfl_xor(a3,m);
                a4 += __shfl_xor(a4,m); a5 += __shfl_xor(a5,m);
                a6 += __shfl_xor(a6,m); a7 += __shfl_xor(a7,m);
            }
            if (q==0){
                float4 b0 = *(const float4*)(bpp + j0);
                float4 b1 = *(const float4*)(bpp + j0 + 4);
                prm[j0  ] = clipf(a0+b0.x); prm[j0+1] = clipf(a1+b0.y);
                prm[j0+2] = clipf(a2+b0.z); prm[j0+3] = clipf(a3+b0.w);
                prm[j0+4] = clipf(a4+b1.x); prm[j0+5] = clipf(a5+b1.y);
                prm[j0+6] = clipf(a6+b1.z); prm[j0+7] = clipf(a7+b1.w);
            }
        }
        __syncthreads();

        // E: head params
        if (t < 2*MM){ int h=t>>6, m=t&63; kv[h][m] = tanhf(prm[h*PER_+m]); }
        else if (t < 3*MM){ int m=t-2*MM; ebuf[m] = sigf(prm[HH*PER_ + m]); }
        else if (t < 4*MM){ int m=t-3*MM; abuf[m] = tanhf(prm[HH*PER_ + MM + m]); }
        else if (t < 4*MM+2){
            int h = t-4*MM;
            const float* hp = prm + h*PER_;
            scal[h]   = splus(hp[MM]);
            scal[2+h] = sigf(hp[MM+1]);
            scal[4+h] = 1.0f + splus(hp[MM+2+SS]);
            float p0=hp[MM+2], p1=hp[MM+3], p2=hp[MM+4];
            float mx = fmaxf(p0,fmaxf(p1,p2));
            float e0=expf(p0-mx), e1=expf(p1-mx), e2=expf(p2-mx);
            float s = e0+e1+e2;
            scal[6+3*h]=e0/s; scal[7+3*h]=e1/s; scal[8+3*h]=e2/s;
        }
        __syncthreads();

        // F: inner products k.Mem ; all 1024 threads, 4-way m-split
        {
            const int h = t>>9, n = (t>>2)&127, q = t&3;
            const int m0 = q*16;
            float s=0.f;
            #pragma unroll 8
            for (int m=m0; m<m0+16; ++m) s = fmaf(kv[h][m], Mem[n][m], s);
            s += __shfl_xor(s,1); s += __shfl_xor(s,2);
            if (q==0) innr[h][n] = s;
        }
        __syncthreads();

        // G1: key norm + content softmax + interpolation  (2 waves)
        if (t < 128){
            int h=t>>6, l=t&63;
            float kvl = kv[h][l];
            float kn2 = kvl*kvl;
            for (int off=32; off>=1; off>>=1) kn2 += __shfl_xor(kn2, off);
            float kn = sqrtf(kn2);
            float beta = scal[h], g = scal[2+h];
            float bk0 = beta * innr[h][l]   /(kn*Mn[l]   +1e-8f);
            float bk1 = beta * innr[h][l+64]/(kn*Mn[l+64]+1e-8f);
            float mx = fmaxf(bk0,bk1);
            for (int off=32; off>=1; off>>=1) mx = fmaxf(mx, __shfl_xor(mx, off));
            float e0=expf(bk0-mx), e1=expf(bk1-mx);
            float s=e0+e1;
            for (int off=32; off>=1; off>>=1) s += __shfl_xor(s, off);
            float wc0=e0/s, wc1=e1/s;
            wgs[h][l]    = g*wc0 + (1.f-g)*wprev[h][l];
            wgs[h][l+64] = g*wc1 + (1.f-g)*wprev[h][l+64];
        }
        __syncthreads();

        // G2: shift conv, sharpen, normalize  (2 waves)
        if (t < 128){
            int h=t>>6, l=t&63;
            float gamma = scal[4+h];
            float s0=scal[6+3*h], s1=scal[7+3*h], s2=scal[8+3*h];
            int n0=l, n1=l+64;
            float wt0 = s0*wgs[h][(n0+1)&127] + s1*wgs[h][n0] + s2*wgs[h][(n0+127)&127];
            float wt1 = s0*wgs[h][(n1+1)&127] + s1*wgs[h][n1] + s2*wgs[h][(n1+127)&127];
            float wp0 = powf(wt0, gamma), wp1 = powf(wt1, gamma);
            float s = wp0+wp1;
            for (int off=32; off>=1; off>>=1) s += __shfl_xor(s, off);
            float inv = 1.0f/(s+1e-8f);
            float v0 = wp0*inv, v1 = wp1*inv;
            wcur[h][n0]=v0; wcur[h][n1]=v1;
            wprev[h][n0]=v0; wprev[h][n1]=v1;
        }
        __syncthreads();

        // H: memory write + row norms (wave w handles rows w, w+16, ...)
        {
            float el = ebuf[ln], al = abuf[ln];
            #pragma unroll
            for (int k=0;k<8;++k){
                int n = wv + 16*k;
                float ww = wcur[1][n];
                float v = Mem[n][ln]*(1.0f - ww*el) + ww*al;
                Mem[n][ln] = v;
                float sq = v*v;
                for (int off=32; off>=1; off>>=1) sq += __shfl_xor(sq, off);
                if (ln==0) Mn[n] = sqrtf(sq);
            }
        }
        __syncthreads();

        // I: read head r = w_r @ Mem ; wave w covers m=4w..4w+3, 16-way n-split
        {
            const int q = ln>>2, m = 4*wv + (ln&3);
            float s=0.f;
            #pragma unroll 8
            for (int n=q*8; n<q*8+8; ++n) s = fmaf(wcur[0][n], Mem[n][m], s);
            s += __shfl_xor(s,4); s += __shfl_xor(s,8);
            s += __shfl_xor(s,16); s += __shfl_xor(s,32);
            if (ln < 4) rbuf[m] = s;
        }
        __syncthreads();

        // J: output ; A: build vec for step+1
        if (t < 256){
            int o=t>>5, i0=t&31;
            float s=0.f;
            #pragma unroll
            for (int j=0;j<10;++j){
                int i=i0+32*j;
                float v = (i<U_)? hbuf[i] : rbuf[i-U_];
                s = fmaf(v, W_o[i*OUT_ + o], s);
            }
            for (int off=16; off>=1; off>>=1) s += __shfl_xor(s, off, 32);
            if (i0==0 && step>=TSTART){
                float logit = clipf(s + b_o[o]);
                out[((b*(T_-TSTART)) + (step-TSTART))*OUT_ + o] = sigf(logit);
            }
        } else if (t >= 512 && t < 512+KTOT && step+1 < T_){
            int tt = t - 512;
            float v;
            if (tt < IN_DIM_)      v = inputs[(b*T_ + step+1)*IN_DIM_ + tt];
            else if (tt < CTRL_)   v = rbuf[tt-IN_DIM_];
            else                   v = hbuf[tt-CTRL_];
            vec[tt] = v;
        }
        __syncthreads();
    }
}

extern "C" void kernel_launch(void* const* d_in, const int* in_sizes, int n_in,
                              void* d_out, int out_size, void* d_ws, size_t ws_size,
                              hipStream_t stream) {
    const float* inputs = (const float*)d_in[0];
    const float* W_x    = (const float*)d_in[1];
    const float* W_h    = (const float*)d_in[2];
    const float* b_lstm = (const float*)d_in[3];
    const float* W_p    = (const float*)d_in[4];
    const float* b_p    = (const float*)d_in[5];
    const float* W_o    = (const float*)d_in[6];
    const float* b_o    = (const float*)d_in[7];
    const float* r0     = (const float*)d_in[8];
    const float* w0     = (const float*)d_in[9];
    float* out = (float*)d_out;

    char* ws = (char*)d_ws;
    __hip_bfloat16* wxh = (__hip_bfloat16*)(ws + WXH_OFF);
    __hip_bfloat16* wp  = (__hip_bfloat16*)(ws + WP_OFF);
    float* bpp          = (float*)(ws + BPP_OFF);

    prep_kernel<<<512, 256, 0, stream>>>(W_x, W_h, W_p, b_p, wxh, wp, bpp);
    ntm_kernel<<<B_, 1024, 0, stream>>>(inputs, b_lstm, W_o, b_o, r0, w0,
                                        wxh, wp, bpp, out);
}

// Round 4
// 3832.255 us; speedup vs baseline: 2.0428x; 1.1086x over previous
//
#include <hip/hip_runtime.h>
#include <hip/hip_bf16.h>
#include <math.h>

#define U_ 256
#define NN 128
#define MM 64
#define SS 3
#define OUT_ 8
#define CLIPV 20.0f
#define IN_DIM_ 9
#define HH 2
#define PER_ 70
#define PP 268       // H*PER + WH*2*M
#define PPAD 272     // padded params
#define B_ 128
#define T_ 130
#define TSTART 65
#define CTRL_ 73
#define KTOT 329     // CTRL_ + U_

// ws layout (bytes)
#define WXH_OFF 0
#define WXH_ELEMS (KTOT*1024)              // rows 0-72: W_x ; rows 73-328: W_h
#define WP_OFF   (WXH_ELEMS*2)
#define WP_ELEMS (U_*PPAD)
#define BPP_OFF  (WP_OFF + WP_ELEMS*2)
#define PREP_TOT (WXH_ELEMS + WP_ELEMS + PPAD)

__device__ __forceinline__ float sigf(float x){ return 1.0f/(1.0f+expf(-x)); }
__device__ __forceinline__ float splus(float x){ return log1pf(expf(x)); }
__device__ __forceinline__ float clipf(float x){ return fminf(fmaxf(x,-CLIPV),CLIPV); }
__device__ __forceinline__ float blo(unsigned u){ return __uint_as_float(u<<16); }
__device__ __forceinline__ float bhi(unsigned u){ return __uint_as_float(u & 0xffff0000u); }

__global__ void prep_kernel(const float* __restrict__ W_x, const float* __restrict__ W_h,
                            const float* __restrict__ W_p, const float* __restrict__ b_p,
                            __hip_bfloat16* __restrict__ wxh, __hip_bfloat16* __restrict__ wp,
                            float* __restrict__ bpp)
{
    for (int idx = blockIdx.x*blockDim.x + threadIdx.x; idx < PREP_TOT; idx += gridDim.x*blockDim.x){
        if (idx < WXH_ELEMS){
            int i = idx >> 10;
            wxh[idx] = __float2bfloat16(i < CTRL_ ? W_x[idx] : W_h[idx - CTRL_*1024]);
        } else if (idx < WXH_ELEMS + WP_ELEMS){
            int k = idx - WXH_ELEMS;
            int i = k / PPAD, j = k - i*PPAD;
            wp[k] = (j < PP) ? __float2bfloat16(W_p[i*PP + j]) : __float2bfloat16(0.0f);
        } else {
            int j = idx - WXH_ELEMS - WP_ELEMS;
            bpp[j] = (j < PP) ? b_p[j] : 0.0f;
        }
    }
}

__global__ __launch_bounds__(1024,1) void ntm_kernel(
    const float* __restrict__ inputs,
    const float* __restrict__ b_lstm,
    const float* __restrict__ W_o, const float* __restrict__ b_o,
    const float* __restrict__ r0, const float* __restrict__ w0,
    const __hip_bfloat16* __restrict__ wxh, const __hip_bfloat16* __restrict__ wp,
    const float* __restrict__ bpp,
    float* __restrict__ out)
{
    const int b = blockIdx.x;
    const int t = threadIdx.x;
    const int wv = t >> 6, ln = t & 63;
    const __hip_bfloat16* __restrict__ whh = wxh + CTRL_*1024;

    __shared__ float Mem[NN][MM+1];
    __shared__ float hbuf[U_], cbuf[U_];
    __shared__ float gates[4*U_];
    __shared__ float gpart[4*U_];     // h@W_h, computed one step ahead
    __shared__ float xr[CTRL_];       // [x_t (9); r_{t-1} (64)]
    __shared__ float prm[PPAD];
    __shared__ float jpart[OUT_];     // h@W_o (h-part)
    __shared__ float kv[HH][MM];
    __shared__ float ebuf[MM], abuf[MM];
    __shared__ float knb[HH];
    __shared__ float scal[12];        // 0,1 beta; 2,3 g; 4,5 gamma; 6..11 s
    __shared__ float innr[HH][NN];
    __shared__ float Mn[NN];
    __shared__ float wgs[HH][NN];
    __shared__ float wcur[HH][NN];
    __shared__ float wprev[HH][NN];
    __shared__ float rpart[16][MM];

    // ---- init state ----
    for (int idx=t; idx<NN*MM; idx+=1024){ Mem[idx>>6][idx&63] = 1e-6f; }
    gpart[t] = 0.f;
    if (t < NN) Mn[t] = sqrtf((float)MM * 1e-6f * 1e-6f);
    if (t < U_){ hbuf[t]=0.f; cbuf[t]=0.f; }
    if (t < IN_DIM_) xr[t] = inputs[b*T_*IN_DIM_ + t];
    else if (t < CTRL_) xr[t] = tanhf(r0[t-IN_DIM_]);
    if (t >= 128 && t < 256){  // wprev = softmax(w0)
        int h = (t-128)>>6, l = t&63;
        float v0 = w0[h*NN + l], v1 = w0[h*NN + l + 64];
        float mx = fmaxf(v0,v1);
        for (int off=32; off>=1; off>>=1) mx = fmaxf(mx, __shfl_xor(mx, off));
        float e0 = expf(v0-mx), e1 = expf(v1-mx);
        float s = e0+e1;
        for (int off=32; off>=1; off>>=1) s += __shfl_xor(s, off);
        wprev[h][l] = e0/s; wprev[h][l+64] = e1/s;
    }
    __syncthreads();

    for (int step=0; step<T_; ++step){
        // B: gates = xr @ W_x + gpart + b  (K=73 only; 128 col-grps x 8-way K)
        {
            const int g = t>>3, q = t&7, j0 = g*8;
            const int k0 = (q*CTRL_)>>3, k1 = ((q+1)*CTRL_)>>3;
            float a0=0.f,a1=0.f,a2=0.f,a3=0.f,a4=0.f,a5=0.f,a6=0.f,a7=0.f;
            #pragma unroll 3
            for (int i=k0; i<k1; ++i){
                float v = xr[i];
                uint4 u = *(const uint4*)(wxh + (i<<10) + j0);
                a0 = fmaf(v, blo(u.x), a0); a1 = fmaf(v, bhi(u.x), a1);
                a2 = fmaf(v, blo(u.y), a2); a3 = fmaf(v, bhi(u.y), a3);
                a4 = fmaf(v, blo(u.z), a4); a5 = fmaf(v, bhi(u.z), a5);
                a6 = fmaf(v, blo(u.w), a6); a7 = fmaf(v, bhi(u.w), a7);
            }
            #pragma unroll
            for (int m=1; m<8; m<<=1){
                a0 += __shfl_xor(a0,m); a1 += __shfl_xor(a1,m);
                a2 += __shfl_xor(a2,m); a3 += __shfl_xor(a3,m);
                a4 += __shfl_xor(a4,m); a5 += __shfl_xor(a5,m);
                a6 += __shfl_xor(a6,m); a7 += __shfl_xor(a7,m);
            }
            if (q==0){
                float4 b0 = *(const float4*)(b_lstm + j0);
                float4 b1 = *(const float4*)(b_lstm + j0 + 4);
                float4 g0 = *(const float4*)(gpart + j0);
                float4 g1 = *(const float4*)(gpart + j0 + 4);
                *(float4*)&gates[j0]   = make_float4(a0+b0.x+g0.x, a1+b0.y+g0.y, a2+b0.z+g0.z, a3+b0.w+g0.w);
                *(float4*)&gates[j0+4] = make_float4(a4+b1.x+g1.x, a5+b1.y+g1.y, a6+b1.z+g1.z, a7+b1.w+g1.w);
            }
        }
        __syncthreads();

        // C: LSTM cell
        if (t < U_){
            float gi = gates[t], gf = gates[t+U_], gg_ = gates[t+2*U_], go = gates[t+3*U_];
            float c = sigf(gf)*cbuf[t] + sigf(gi)*tanhf(gg_);
            cbuf[t] = c;
            hbuf[t] = sigf(go)*tanhf(c);
        }
        __syncthreads();

        // FUSED: everything that depends only on h
        if (t < 512){
            // gpart = h @ W_h  (for NEXT step): 128 col-grps of 8, 4-way K
            const int g = t>>2, q = t&3, j0 = g*8;
            const int k0 = q*64, k1 = k0+64;
            float a0=0.f,a1=0.f,a2=0.f,a3=0.f,a4=0.f,a5=0.f,a6=0.f,a7=0.f;
            #pragma unroll 4
            for (int i=k0; i<k1; ++i){
                float v = hbuf[i];
                uint4 u = *(const uint4*)(whh + (i<<10) + j0);
                a0 = fmaf(v, blo(u.x), a0); a1 = fmaf(v, bhi(u.x), a1);
                a2 = fmaf(v, blo(u.y), a2); a3 = fmaf(v, bhi(u.y), a3);
                a4 = fmaf(v, blo(u.z), a4); a5 = fmaf(v, bhi(u.z), a5);
                a6 = fmaf(v, blo(u.w), a6); a7 = fmaf(v, bhi(u.w), a7);
            }
            #pragma unroll
            for (int m=1; m<4; m<<=1){
                a0 += __shfl_xor(a0,m); a1 += __shfl_xor(a1,m);
                a2 += __shfl_xor(a2,m); a3 += __shfl_xor(a3,m);
                a4 += __shfl_xor(a4,m); a5 += __shfl_xor(a5,m);
                a6 += __shfl_xor(a6,m); a7 += __shfl_xor(a7,m);
            }
            if (q==0){
                *(float4*)&gpart[j0]   = make_float4(a0,a1,a2,a3);
                *(float4*)&gpart[j0+4] = make_float4(a4,a5,a6,a7);
            }
        } else if (t < 784){
            // prm = clip(h @ W_p + b): 34 col-grps of 8, 8-way K
            const int tt = t-512, g = tt>>3, q = tt&7, j0 = g*8;
            const int k0 = q*32, k1 = k0+32;
            float a0=0.f,a1=0.f,a2=0.f,a3=0.f,a4=0.f,a5=0.f,a6=0.f,a7=0.f;
            #pragma unroll 4
            for (int i=k0; i<k1; ++i){
                float v = hbuf[i];
                uint4 u = *(const uint4*)(wp + i*PPAD + j0);
                a0 = fmaf(v, blo(u.x), a0); a1 = fmaf(v, bhi(u.x), a1);
                a2 = fmaf(v, blo(u.y), a2); a3 = fmaf(v, bhi(u.y), a3);
                a4 = fmaf(v, blo(u.z), a4); a5 = fmaf(v, bhi(u.z), a5);
                a6 = fmaf(v, blo(u.w), a6); a7 = fmaf(v, bhi(u.w), a7);
            }
            #pragma unroll
            for (int m=1; m<8; m<<=1){
                a0 += __shfl_xor(a0,m); a1 += __shfl_xor(a1,m);
                a2 += __shfl_xor(a2,m); a3 += __shfl_xor(a3,m);
                a4 += __shfl_xor(a4,m); a5 += __shfl_xor(a5,m);
                a6 += __shfl_xor(a6,m); a7 += __shfl_xor(a7,m);
            }
            if (q==0){
                float4 b0 = *(const float4*)(bpp + j0);
                float4 b1 = *(const float4*)(bpp + j0 + 4);
                prm[j0  ] = clipf(a0+b0.x); prm[j0+1] = clipf(a1+b0.y);
                prm[j0+2] = clipf(a2+b0.z); prm[j0+3] = clipf(a3+b0.w);
                prm[j0+4] = clipf(a4+b1.x); prm[j0+5] = clipf(a5+b1.y);
                prm[j0+6] = clipf(a6+b1.z); prm[j0+7] = clipf(a7+b1.w);
            }
        } else if (t >= 832 && t < 832+IN_DIM_){
            if (step+1 < T_) xr[t-832] = inputs[(b*T_ + step+1)*IN_DIM_ + (t-832)];
        } else if (t >= 896){
            // jpart[o] = h @ W_o[:256, o]
            const int o = (t-896)>>4, l16 = t&15;
            float s=0.f;
            #pragma unroll 4
            for (int j=0;j<16;++j){
                int i = l16 + (j<<4);
                s = fmaf(hbuf[i], W_o[i*OUT_ + o], s);
            }
            s += __shfl_xor(s,1); s += __shfl_xor(s,2);
            s += __shfl_xor(s,4); s += __shfl_xor(s,8);
            if (l16==0) jpart[o] = s;
        }
        __syncthreads();

        // E: head params (+ key norms)
        if (t < 128){
            int h = t>>6;
            float kvv = tanhf(prm[h*PER_ + ln]);
            kv[h][ln] = kvv;
            float kn2 = kvv*kvv;
            for (int off=32; off>=1; off>>=1) kn2 += __shfl_xor(kn2, off);
            if (ln==0) knb[h] = sqrtf(kn2);
        } else if (t < 192){ ebuf[t-128] = sigf(prm[HH*PER_ + (t-128)]); }
        else if (t < 256){ abuf[t-192] = tanhf(prm[HH*PER_ + MM + (t-192)]); }
        else if (t < 258){
            int h = t-256;
            const float* hp = prm + h*PER_;
            scal[h]   = splus(hp[MM]);
            scal[2+h] = sigf(hp[MM+1]);
            scal[4+h] = 1.0f + splus(hp[MM+2+SS]);
            float p0=hp[MM+2], p1=hp[MM+3], p2=hp[MM+4];
            float mx = fmaxf(p0,fmaxf(p1,p2));
            float e0=expf(p0-mx), e1=expf(p1-mx), e2=expf(p2-mx);
            float s = e0+e1+e2;
            scal[6+3*h]=e0/s; scal[7+3*h]=e1/s; scal[8+3*h]=e2/s;
        }
        __syncthreads();

        // F: inner products (512 thr) + Mem row norms (128 thr)
        if (t < 512){
            const int h = t>>8, n = (t>>1)&127, q = t&1, m0 = q*32;
            float s=0.f;
            #pragma unroll 8
            for (int m=m0; m<m0+32; ++m) s = fmaf(kv[h][m], Mem[n][m], s);
            s += __shfl_xor(s,1);
            if (q==0) innr[h][n] = s;
        } else if (t < 640){
            const int n = t-512;
            float s=0.f;
            #pragma unroll 8
            for (int m=0;m<MM;++m){ float v=Mem[n][m]; s=fmaf(v,v,s); }
            Mn[n] = sqrtf(s);
        }
        __syncthreads();

        // G: content softmax + interp + shift + sharpen (2 waves, no inner barrier)
        if (t < 128){
            const int h = t>>6, l = ln;
            float kn = knb[h], beta = scal[h], g = scal[2+h];
            float bk0 = beta * innr[h][l]   /(kn*Mn[l]   +1e-8f);
            float bk1 = beta * innr[h][l+64]/(kn*Mn[l+64]+1e-8f);
            float mx = fmaxf(bk0,bk1);
            for (int off=32; off>=1; off>>=1) mx = fmaxf(mx, __shfl_xor(mx, off));
            float e0=expf(bk0-mx), e1=expf(bk1-mx);
            float s=e0+e1;
            for (int off=32; off>=1; off>>=1) s += __shfl_xor(s, off);
            float wc0=e0/s, wc1=e1/s;
            wgs[h][l]    = g*wc0 + (1.f-g)*wprev[h][l];
            wgs[h][l+64] = g*wc1 + (1.f-g)*wprev[h][l+64];
            // shift + sharpen + normalize (same wave owns the whole row)
            float gamma = scal[4+h];
            float s0=scal[6+3*h], s1=scal[7+3*h], s2=scal[8+3*h];
            int n0=l, n1=l+64;
            float wt0 = s0*wgs[h][(n0+1)&127] + s1*wgs[h][n0] + s2*wgs[h][(n0+127)&127];
            float wt1 = s0*wgs[h][(n1+1)&127] + s1*wgs[h][n1] + s2*wgs[h][(n1+127)&127];
            float wp0 = powf(wt0, gamma), wp1 = powf(wt1, gamma);
            float ss = wp0+wp1;
            for (int off=32; off>=1; off>>=1) ss += __shfl_xor(ss, off);
            float inv = 1.0f/(ss+1e-8f);
            float v0 = wp0*inv, v1 = wp1*inv;
            wcur[h][n0]=v0; wcur[h][n1]=v1;
            wprev[h][n0]=v0; wprev[h][n1]=v1;
        }
        __syncthreads();

        // H: memory write + fused read-head partials (wave w owns rows 8w..8w+7)
        {
            const float el = ebuf[ln], al = abuf[ln];
            const int n0 = wv*8;
            float racc = 0.f;
            #pragma unroll
            for (int k=0;k<8;++k){
                const int n = n0+k;
                float ww = wcur[1][n];
                float wr = wcur[0][n];
                float v = Mem[n][ln]*(1.0f - ww*el) + ww*al;
                Mem[n][ln] = v;
                racc = fmaf(wr, v, racc);
            }
            rpart[wv][ln] = racc;
        }
        __syncthreads();

        // J: r finalize + output (8 waves, one per output)
        if (t < 512){
            const int o = wv;   // 0..7
            float rm = 0.f;
            #pragma unroll
            for (int k=0;k<16;++k) rm += rpart[k][ln];
            if (o==0) xr[IN_DIM_ + ln] = rm;   // r for next step's ctrl
            float s = rm * W_o[(U_+ln)*OUT_ + o];
            for (int off=32; off>=1; off>>=1) s += __shfl_xor(s, off);
            if (ln==0 && step>=TSTART){
                float logit = clipf(s + jpart[o] + b_o[o]);
                out[((b*(T_-TSTART)) + (step-TSTART))*OUT_ + o] = sigf(logit);
            }
        }
        __syncthreads();
    }
}

extern "C" void kernel_launch(void* const* d_in, const int* in_sizes, int n_in,
                              void* d_out, int out_size, void* d_ws, size_t ws_size,
                              hipStream_t stream) {
    const float* inputs = (const float*)d_in[0];
    const float* W_x    = (const float*)d_in[1];
    const float* W_h    = (const float*)d_in[2];
    const float* b_lstm = (const float*)d_in[3];
    const float* W_p    = (const float*)d_in[4];
    const float* b_p    = (const float*)d_in[5];
    const float* W_o    = (const float*)d_in[6];
    const float* b_o    = (const float*)d_in[7];
    const float* r0     = (const float*)d_in[8];
    const float* w0     = (const float*)d_in[9];
    float* out = (float*)d_out;

    char* ws = (char*)d_ws;
    __hip_bfloat16* wxh = (__hip_bfloat16*)(ws + WXH_OFF);
    __hip_bfloat16* wp  = (__hip_bfloat16*)(ws + WP_OFF);
    float* bpp          = (float*)(ws + BPP_OFF);

    prep_kernel<<<512, 256, 0, stream>>>(W_x, W_h, W_p, b_p, wxh, wp, bpp);
    ntm_kernel<<<B_, 1024, 0, stream>>>(inputs, b_lstm, W_o, b_o, r0, w0,
                                        wxh, wp, bpp, out);
}